// Round 4
// baseline (708.761 us; speedup 1.0000x reference)
//
#include <hip/hip_runtime.h>

typedef unsigned short u16;
typedef __bf16 bf16x8 __attribute__((ext_vector_type(8)));
typedef short s16x4 __attribute__((ext_vector_type(4)));
typedef float f32x4 __attribute__((ext_vector_type(4)));

#define SCALE_ATT 0.0625f   // C^-0.5 = 1/16

static __device__ __forceinline__ u16 f2b(float f) {
    union { float f; unsigned u; } v; v.f = f;
    unsigned r = (v.u + 0x7fffu + ((v.u >> 16) & 1u)) >> 16;
    return (u16)r;
}
static __device__ __forceinline__ float b2f(u16 h) {
    union { unsigned u; float f; } v; v.u = ((unsigned)h) << 16;
    return v.f;
}

#if defined(__has_builtin)
#if __has_builtin(__builtin_amdgcn_mfma_f32_16x16x16bf16_1k)
#define HAVE_MFMA16 1
#endif
#if __has_builtin(__builtin_amdgcn_global_load_lds)
#define HAVE_GLOADLDS 1
#endif
#endif

static __device__ __forceinline__ f32x4 mfma16(s16x4 a, s16x4 b, f32x4 c) {
#ifdef HAVE_MFMA16
    return __builtin_amdgcn_mfma_f32_16x16x16bf16_1k(a, b, c, 0, 0, 0);
#else
    f32x4 d;
    asm volatile("v_mfma_f32_16x16x16_bf16 %0, %1, %2, %3\n\ts_nop 7\n\ts_nop 7"
                 : "=v"(d) : "v"(a), "v"(b), "v"(c));
    return d;
#endif
}

#ifdef HAVE_GLOADLDS
static __device__ __forceinline__ void gload16(const u16* g, u16* l) {
    __builtin_amdgcn_global_load_lds(
        (const __attribute__((address_space(1))) void*)g,
        (__attribute__((address_space(3))) void*)l, 16, 0, 0);
}
#endif

// ---------------------------------------------------------------------------
// Weight transpose + bf16 cast: src [R][C] f32 -> dst [C][R] bf16
__global__ void wtrans_kernel(const float* __restrict__ src, u16* __restrict__ dst,
                              int R, int C) {
    int i = blockIdx.x * 256 + threadIdx.x;
    if (i >= R * C) return;
    int r = i / C, c = i % C;
    dst[(size_t)c * R + r] = f2b(src[i]);
}

// ---------------------------------------------------------------------------
// LN1 + NCHW->NHWC transpose. Block = (n,y). Writes xp (raw x, NHWC f32),
// ln1 (bf16 NHWC), and per-(y, window-col) pooled partial sums (fp32 LN vals).
__global__ __launch_bounds__(256) void ln_xpose_kernel(
    const float* __restrict__ x, const float* __restrict__ g, const float* __restrict__ b,
    float* __restrict__ xp, u16* __restrict__ ln1, float* __restrict__ pool_part) {
    __shared__ float xs[256][65];
    __shared__ float ps[4][64], ps2[4][64];
    __shared__ float mvmu[64], mvrs[64];
    int nb = blockIdx.x; int n = nb >> 6, y = nb & 63;
    int t = threadIdx.x;
    const float4* src = (const float4*)(x + ((size_t)(n * 256 + t) * 64 + y) * 64);
    for (int x4 = 0; x4 < 16; ++x4) {
        float4 v = src[x4];
        xs[t][x4 * 4 + 0] = v.x; xs[t][x4 * 4 + 1] = v.y;
        xs[t][x4 * 4 + 2] = v.z; xs[t][x4 * 4 + 3] = v.w;
    }
    __syncthreads();
    int part = t >> 6, l = t & 63;
    float s1 = 0.f, s2 = 0.f;
    for (int c = 0; c < 64; ++c) { float v = xs[part * 64 + c][l]; s1 += v; s2 += v * v; }
    ps[part][l] = s1; ps2[part][l] = s2;
    __syncthreads();
    if (t < 64) {
        float su = ps[0][t] + ps[1][t] + ps[2][t] + ps[3][t];
        float sq = ps2[0][t] + ps2[1][t] + ps2[2][t] + ps2[3][t];
        float mu = su * (1.f / 256.f);
        float var = sq * (1.f / 256.f) - mu * mu;
        mvmu[t] = mu; mvrs[t] = rsqrtf(var + 1e-6f);
    }
    __syncthreads();
    float gc = g[t], bc = b[t];
    size_t tokbase = (size_t)nb * 64;
    float pw = 0.f;
    for (int xx = 0; xx < 64; ++xx) {
        float raw = xs[t][xx];
        float val = (raw - mvmu[xx]) * mvrs[xx] * gc + bc;
        size_t tok = tokbase + xx;
        xp[tok * 256 + t] = raw;
        ln1[tok * 256 + t] = f2b(val);
        pw += val;
        if ((xx & 7) == 7) {
            pool_part[((size_t)nb * 8 + (xx >> 3)) * 256 + t] = pw;
            pw = 0.f;
        }
    }
}

// pooled[n][p][c] = mean over 64 window pixels (from y-row partials)
__global__ void pool_reduce_kernel(const float* __restrict__ pool_part,
                                   float* __restrict__ pooled) {
    int nb = blockIdx.x; int n = nb >> 6, p = nb & 63;
    int wi = p >> 3, wj = p & 7;
    int t = threadIdx.x;
    float s = 0.f;
    for (int r = 0; r < 8; ++r)
        s += pool_part[((size_t)((n * 64 + wi * 8 + r) * 8 + wj)) * 256 + t];
    pooled[(size_t)nb * 256 + t] = s * (1.f / 64.f);
}

// q_win/k_win = pooled @ Wq/Wk + b  (fp32, tiny). qk_win[nb][0:256]=q, [256:512]=k
__global__ void qkwin_kernel(const float* __restrict__ pooled,
                             const float* __restrict__ qkv_w, const float* __restrict__ qkv_b,
                             float* __restrict__ qk_win) {
    __shared__ float pr[256];
    int nb = blockIdx.x; int t = threadIdx.x;
    pr[t] = pooled[(size_t)nb * 256 + t];
    __syncthreads();
    float aq = qkv_b[t], ak = qkv_b[256 + t];
    for (int k = 0; k < 256; ++k) {
        float pv = pr[k];
        aq += pv * qkv_w[(size_t)k * 768 + t];
        ak += pv * qkv_w[(size_t)k * 768 + 256 + t];
    }
    qk_win[(size_t)nb * 512 + t] = aq;
    qk_win[(size_t)nb * 512 + 256 + t] = ak;
}

// top-4 window routing (sequential argmax == jax.lax.top_k tie rule: lowest idx)
__global__ void routing_kernel(const float* __restrict__ qk_win, int* __restrict__ idxp) {
    __shared__ float lg_[64];
    int nb = blockIdx.x; int n = nb >> 6;
    int t = threadIdx.x;  // 64 threads
    const float* qw = qk_win + (size_t)nb * 512;
    const float* kw = qk_win + (size_t)(n * 64 + t) * 512 + 256;
    float s = 0.f;
    for (int c = 0; c < 256; ++c) s += qw[c] * kw[c];
    lg_[t] = s * SCALE_ATT;
    __syncthreads();
    if (t == 0) {
        for (int j = 0; j < 4; ++j) {
            float best = -INFINITY; int bi = 0;
            for (int q = 0; q < 64; ++q) if (lg_[q] > best) { best = lg_[q]; bi = q; }
            idxp[nb * 4 + j] = bi;
            lg_[bi] = -INFINITY;
        }
    }
}

// ---------------------------------------------------------------------------
// bf16 GEMM, m97 structure: 128x128 tile, BK=32, 4 waves, 4x4 16x16 frags/wave.
// global_load_lds width-16 into linear LDS; read-side XOR swizzle implemented
// by pre-swizzling the per-lane GLOBAL source (cseg ^= (row>>1)&3) -- rule #21.
// EPI 0: ->bf16. EPI 1: gelu(exact)->bf16. EPI 2: resid_out = resid_in + gamma*val
template <int EPI>
__global__ __launch_bounds__(256) void gemm_kernel(
    const u16* __restrict__ A, const u16* __restrict__ Bt,
    const float* __restrict__ bias, u16* __restrict__ outb,
    int M, int Nn, int K,
    const float* __restrict__ resid_in, const float* __restrict__ gamma,
    float* __restrict__ resid_out) {
    __shared__ u16 As[4096];   // [128 rows][32 k] linear (row = granule>>2)
    __shared__ u16 Bs[4096];
    int t = threadIdx.x;
    int rowBase = blockIdx.x * 128, colBase = blockIdx.y * 128;
    int wid = t >> 6, lane = t & 63;
    int wr = (wid >> 1) * 64, wc = (wid & 1) * 64;
    int lr = lane & 15, g = lane >> 4;
    f32x4 acc[4][4] = {};

    // staging geometry: wave covers granules (wid*2+j)*64 + lane, j=0,1
    int rA0 = wid * 32 + (lane >> 2);      // tile row for j=0
    int rA1 = rA0 + 16;                    // tile row for j=1
    int cs0 = (lane & 3) ^ ((rA0 >> 1) & 3);   // swizzled k-seg (involution)
    int cs1 = (lane & 3) ^ ((rA1 >> 1) & 3);
    const u16* gA0 = A + (size_t)(rowBase + rA0) * K + cs0 * 8;
    const u16* gA1 = A + (size_t)(rowBase + rA1) * K + cs1 * 8;
    const u16* gB0 = Bt + (size_t)(colBase + rA0) * K + cs0 * 8;
    const u16* gB1 = Bt + (size_t)(colBase + rA1) * K + cs1 * 8;
    u16* lA0 = &As[(wid * 2 + 0) * 512];
    u16* lA1 = &As[(wid * 2 + 1) * 512];
    u16* lB0 = &Bs[(wid * 2 + 0) * 512];
    u16* lB1 = &Bs[(wid * 2 + 1) * 512];

    // read-side swizzled column byte offset (lane-constant)
    int cSwz = (g * 16) ^ (((lr >> 1) & 3) << 4);
    const char* pA = (const char*)As;
    const char* pB = (const char*)Bs;

    for (int k0 = 0; k0 < K; k0 += 32) {
#ifdef HAVE_GLOADLDS
        gload16(gA0 + k0, lA0);
        gload16(gA1 + k0, lA1);
        gload16(gB0 + k0, lB0);
        gload16(gB1 + k0, lB1);
        __syncthreads();                    // vmcnt drained -> LDS tile ready
#else
        float4 a0 = *(const float4*)(gA0 + k0);
        float4 a1 = *(const float4*)(gA1 + k0);
        float4 b0 = *(const float4*)(gB0 + k0);
        float4 b1 = *(const float4*)(gB1 + k0);
        __syncthreads();                    // prev reads done
        *(float4*)&lA0[lane * 8] = a0;
        *(float4*)&lA1[lane * 8] = a1;
        *(float4*)&lB0[lane * 8] = b0;
        *(float4*)&lB1[lane * 8] = b1;
        __syncthreads();                    // tile ready
#endif
        bf16x8 af[4], bf[4];
        #pragma unroll
        for (int m = 0; m < 4; ++m)
            af[m] = *(const bf16x8*)(pA + (wr + m * 16 + lr) * 64 + cSwz);
        #pragma unroll
        for (int nn = 0; nn < 4; ++nn)
            bf[nn] = *(const bf16x8*)(pB + (wc + nn * 16 + lr) * 64 + cSwz);
        #pragma unroll
        for (int m = 0; m < 4; ++m)
            #pragma unroll
            for (int nn = 0; nn < 4; ++nn)
                acc[m][nn] = __builtin_amdgcn_mfma_f32_16x16x32_bf16(af[m], bf[nn], acc[m][nn], 0, 0, 0);
#ifdef HAVE_GLOADLDS
        __syncthreads();                    // reads done -> safe to overwrite
#endif
    }

    for (int m = 0; m < 4; ++m)
        for (int nn = 0; nn < 4; ++nn) {
            int col = colBase + wc + nn * 16 + lr;
            float bcol = bias[col];
            for (int r = 0; r < 4; ++r) {
                int row = rowBase + wr + m * 16 + g * 4 + r;
                float v = acc[m][nn][r] + bcol;
                if constexpr (EPI == 0) {
                    outb[(size_t)row * Nn + col] = f2b(v);
                } else if constexpr (EPI == 1) {
                    float gl = 0.5f * v * (1.f + erff(v * 0.70710678118654752f));
                    outb[(size_t)row * Nn + col] = f2b(gl);
                } else {
                    float yv = resid_in[(size_t)row * 256 + col] + gamma[col] * v;
                    resid_out[(size_t)row * 256 + col] = yv;
                }
            }
        }
}

// ---------------------------------------------------------------------------
// 5x5 depthwise conv on v (= qkv[..., 512:]) + bias -> lepe (bf16 NHWC)
// Register sliding-window: grid (512 rows, 4 ch-groups), thread = (16-x strip, ch).
__global__ __launch_bounds__(256) void lepe_kernel(
    const u16* __restrict__ qkv, const float* __restrict__ w,
    const float* __restrict__ bias, u16* __restrict__ lepe) {
    int nb = blockIdx.x, cg = blockIdx.y;
    int n = nb >> 6, y = nb & 63;
    int t = threadIdx.x;
    int c = cg * 64 + (t & 63);
    int x0 = (t >> 6) * 16;
    float wv[25];
    #pragma unroll
    for (int i = 0; i < 25; ++i) wv[i] = w[i * 256 + c];
    float bc = bias[c];
    const u16* vbase = qkv + 512 + c;
    size_t rowstr = (size_t)64 * 768;
    const u16* rbase = vbase + (size_t)(n * 64) * rowstr;
    bool rv[5];
    #pragma unroll
    for (int r = 0; r < 5; ++r) { int yy = y - 2 + r; rv[r] = (yy >= 0 && yy <= 63); }
    float win[5][5];
    #pragma unroll
    for (int r = 0; r < 5; ++r) {
        int yy = y - 2 + r;
        #pragma unroll
        for (int j = 0; j < 4; ++j) {
            int x2 = x0 - 2 + j;
            win[r][j] = (rv[r] && x2 >= 0) ? b2f(rbase[((size_t)yy * 64 + x2) * 768]) : 0.f;
        }
    }
    #pragma unroll
    for (int xi = 0; xi < 16; ++xi) {
        int xx = x0 + xi;
        int xl = xx + 2;
        #pragma unroll
        for (int r = 0; r < 5; ++r) {
            int yy = y - 2 + r;
            win[r][4] = (rv[r] && xl <= 63) ? b2f(rbase[((size_t)yy * 64 + xl) * 768]) : 0.f;
        }
        float s = bc;
        #pragma unroll
        for (int r = 0; r < 5; ++r)
            #pragma unroll
            for (int j = 0; j < 5; ++j)
                s = fmaf(wv[r * 5 + j], win[r][j], s);
        lepe[((size_t)nb * 64 + xx) * 256 + c] = f2b(s);
        #pragma unroll
        for (int r = 0; r < 5; ++r)
            #pragma unroll
            for (int j = 0; j < 4; ++j)
                win[r][j] = win[r][j + 1];
    }
}

// ---------------------------------------------------------------------------
// Routed window attention, swapped-QK^T in-register-softmax form.
// Grid (512 windows, 8 head-pairs), 512 threads = 8 waves.
__global__ __launch_bounds__(512) void attn_kernel(
    const u16* __restrict__ qkv, const int* __restrict__ idxp,
    float* __restrict__ attn_out) {
    __shared__ u16 qs[64][40];     // [pix][32ch], pad->40
    __shared__ u16 ks[256][40];    // [key][32ch], pad->40
    __shared__ u16 vts[32][256];   // [ch][key], XOR-swizzled cols
    __shared__ float os[64][36];   // [pix][32ch] f32 out-stage
    int nb = blockIdx.x, hg = blockIdx.y;
    int n = nb >> 6, p = nb & 63;
    int y0 = (p >> 3) * 8, x0 = (p & 7) * 8;
    int t = threadIdx.x;
    int w0 = idxp[nb * 4 + 0], w1 = idxp[nb * 4 + 1];
    int w2 = idxp[nb * 4 + 2], w3 = idxp[nb * 4 + 3];
    {   // stage Q: 64 tok x 32 ch, 8B per thread
        int tok = t >> 3, seg = t & 7;
        int tokg = (n * 64 + y0 + (tok >> 3)) * 64 + x0 + (tok & 7);
        *(uint2*)&qs[tok][seg * 4] =
            *(const uint2*)(qkv + (size_t)tokg * 768 + hg * 32 + seg * 4);
    }
    {   // stage K (rows) and V (transposed+swizzled): 32B per thread each
        int key = t & 255, half = t >> 8;
        int ws = (key >> 6) == 0 ? w0 : (key >> 6) == 1 ? w1 : (key >> 6) == 2 ? w2 : w3;
        int kp = key & 63;
        int tokk = (n * 64 + (ws >> 3) * 8 + (kp >> 3)) * 64 + (ws & 7) * 8 + (kp & 7);
        const u16* kbase = qkv + (size_t)tokk * 768 + 256 + hg * 32 + half * 16;
        *(float4*)&ks[key][half * 16] = *(const float4*)kbase;
        *(float4*)&ks[key][half * 16 + 8] = *(const float4*)(kbase + 8);
        const u16* vbase = kbase + 256;
        union { float4 f[2]; u16 u[16]; } vu;
        vu.f[0] = *(const float4*)vbase;
        vu.f[1] = *(const float4*)(vbase + 8);
        #pragma unroll
        for (int c2 = 0; c2 < 16; ++c2)
            vts[half * 16 + c2][key ^ (c2 << 2)] = vu.u[c2];
    }
    __syncthreads();

    int wid = t >> 6, lane = t & 63, lr = lane & 15, g = lane >> 4;
    int hh = wid & 1, q0 = (wid >> 1) * 16, c0 = hh * 16;
    f32x4 zf4 = {0.f, 0.f, 0.f, 0.f};
    s16x4 qf = *(const s16x4*)&qs[q0 + lr][c0 + g * 4];
    f32x4 sacc[16];
    #pragma unroll
    for (int kt = 0; kt < 16; ++kt) {
        s16x4 kf = *(const s16x4*)&ks[kt * 16 + lr][c0 + g * 4];
        sacc[kt] = mfma16(kf, qf, zf4);
    }
    // row max over 256 keys: 64 in-lane + xor16 + xor32
    float mx = -INFINITY;
    #pragma unroll
    for (int kt = 0; kt < 16; ++kt) {
        #pragma unroll
        for (int r = 0; r < 4; ++r) mx = fmaxf(mx, sacc[kt][r]);
    }
    mx = fmaxf(mx, __shfl_xor(mx, 16, 64));
    mx = fmaxf(mx, __shfl_xor(mx, 32, 64));
    const float k1 = 0.09016844005556021f;  // SCALE_ATT * log2(e)
    float dsum = 0.f;
    s16x4 pf[16];
    #pragma unroll
    for (int kt = 0; kt < 16; ++kt) {
        #pragma unroll
        for (int r = 0; r < 4; ++r) {
            float pv = exp2f((sacc[kt][r] - mx) * k1);
            dsum += pv;
            pf[kt][r] = (short)f2b(pv);
        }
    }
    dsum += __shfl_xor(dsum, 16, 64);
    dsum += __shfl_xor(dsum, 32, 64);
    float rden = 1.f / dsum;
    // PV: O^T[d][q] += V^T-frag x P-frag, two parallel accumulators
    f32x4 o0 = zf4, o1 = zf4;
    #pragma unroll
    for (int kt = 0; kt < 16; kt += 2) {
        s16x4 v0 = *(const s16x4*)&vts[c0 + lr][(kt * 16 + g * 4) ^ (lr << 2)];
        o0 = mfma16(v0, pf[kt], o0);
        s16x4 v1 = *(const s16x4*)&vts[c0 + lr][((kt + 1) * 16 + g * 4) ^ (lr << 2)];
        o1 = mfma16(v1, pf[kt + 1], o1);
    }
    #pragma unroll
    for (int r = 0; r < 4; ++r)
        os[q0 + lr][c0 + g * 4 + r] = (o0[r] + o1[r]) * rden;
    __syncthreads();
    {   // coalesced writeout: 64 tok x 32 ch f32
        int tok = t >> 3, cs = (t & 7) * 4;
        int tokg = (n * 64 + y0 + (tok >> 3)) * 64 + x0 + (tok & 7);
        *(float4*)(attn_out + (size_t)tokg * 256 + hg * 32 + cs) =
            *(const float4*)&os[tok][cs];
    }
}

// ---------------------------------------------------------------------------
// xp1 = xp + g1*(attn + lepe); LN2 -> z (bf16). Block = one token.
__global__ __launch_bounds__(256) void resid1_ln2_kernel(
    const float* __restrict__ xp, const float* __restrict__ attn,
    const u16* __restrict__ lepe, const float* __restrict__ g1,
    const float* __restrict__ n2g, const float* __restrict__ n2b,
    float* __restrict__ xp1, u16* __restrict__ z) {
    __shared__ float w1s[4], w2s[4];
    size_t tok = blockIdx.x;
    int t = threadIdx.x;
    float x1 = xp[tok * 256 + t] + g1[t] * (attn[tok * 256 + t] + b2f(lepe[tok * 256 + t]));
    xp1[tok * 256 + t] = x1;
    float s1 = x1, s2 = x1 * x1;
    for (int off = 1; off < 64; off <<= 1) {
        s1 += __shfl_xor(s1, off, 64);
        s2 += __shfl_xor(s2, off, 64);
    }
    int wid = t >> 6;
    if ((t & 63) == 0) { w1s[wid] = s1; w2s[wid] = s2; }
    __syncthreads();
    s1 = w1s[0] + w1s[1] + w1s[2] + w1s[3];
    s2 = w2s[0] + w2s[1] + w2s[2] + w2s[3];
    float mu = s1 * (1.f / 256.f);
    float var = s2 * (1.f / 256.f) - mu * mu;
    float rs = rsqrtf(var + 1e-6f);
    z[tok * 256 + t] = f2b((x1 - mu) * rs * n2g[t] + n2b[t]);
}

// NHWC f32 -> NCHW f32 output transpose
__global__ __launch_bounds__(256) void out_xpose_kernel(
    const float* __restrict__ yout, float* __restrict__ outp) {
    __shared__ float ys[256][65];
    int nb = blockIdx.x; int n = nb >> 6, y = nb & 63;
    int t = threadIdx.x;
    for (int xx = 0; xx < 64; ++xx)
        ys[t][xx] = yout[((size_t)nb * 64 + xx) * 256 + t];
    __syncthreads();
    float4* dst = (float4*)(outp + ((size_t)(n * 256 + t) * 64 + y) * 64);
    for (int x4 = 0; x4 < 16; ++x4) {
        float4 v = { ys[t][x4 * 4 + 0], ys[t][x4 * 4 + 1],
                     ys[t][x4 * 4 + 2], ys[t][x4 * 4 + 3] };
        dst[x4] = v;
    }
}

// ---------------------------------------------------------------------------
extern "C" void kernel_launch(void* const* d_in, const int* in_sizes, int n_in,
                              void* d_out, int out_size, void* d_ws, size_t ws_size,
                              hipStream_t stream) {
    (void)in_sizes; (void)n_in; (void)out_size; (void)ws_size;
    const float* x      = (const float*)d_in[0];
    const float* n1g    = (const float*)d_in[1];
    const float* n1b    = (const float*)d_in[2];
    const float* qkv_w  = (const float*)d_in[3];
    const float* qkv_b  = (const float*)d_in[4];
    const float* lepe_w = (const float*)d_in[5];
    const float* lepe_b = (const float*)d_in[6];
    const float* g1     = (const float*)d_in[7];
    const float* g2     = (const float*)d_in[8];
    const float* n2g    = (const float*)d_in[9];
    const float* n2b    = (const float*)d_in[10];
    const float* w1     = (const float*)d_in[11];
    const float* b1     = (const float*)d_in[12];
    const float* w2     = (const float*)d_in[13];
    const float* b2     = (const float*)d_in[14];
    float* outp = (float*)d_out;
    char* ws = (char*)d_ws;

    // workspace layout (total ~175 MB)
    float* xp        = (float*)(ws + 0);            // 33,554,432
    u16*   ln1       = (u16*)(ws + 33554432);       // 16,777,216
    u16*   qkv       = (u16*)(ws + 50331648);       // 50,331,648
    float* attn_out  = (float*)(ws + 100663296);    // 33,554,432 (reused as yout)
    u16*   lepe      = (u16*)(ws + 134217728);      // 16,777,216
    u16*   zbuf      = (u16*)(ws + 150994944);      // 16,777,216
    float* pool_part = (float*)(ws + 167772160);    //  4,194,304
    float* pooled    = (float*)(ws + 171966464);    //    524,288
    float* qk_win    = (float*)(ws + 172490752);    //  1,048,576
    int*   idxb      = (int*)(ws + 173539328);      //      8,192
    u16*   wt_qkv    = (u16*)(ws + 173547520);      //    393,216
    u16*   wt_m1     = (u16*)(ws + 173940736);      //    524,288
    u16*   wt_m2     = (u16*)(ws + 174465024);      //    524,288  (end 174,989,312)
    u16*   hbuf      = ln1;       // [32768][1024] bf16 reuses ln1+qkv region (exactly 64 MB)
    float* xp1       = outp;      // d_out used as scratch; fully overwritten by out_xpose
    float* yout      = attn_out;

    wtrans_kernel<<<768, 256, 0, stream>>>(qkv_w, wt_qkv, 256, 768);
    wtrans_kernel<<<1024, 256, 0, stream>>>(w1, wt_m1, 256, 1024);
    wtrans_kernel<<<1024, 256, 0, stream>>>(w2, wt_m2, 1024, 256);

    ln_xpose_kernel<<<512, 256, 0, stream>>>(x, n1g, n1b, xp, ln1, pool_part);
    pool_reduce_kernel<<<512, 256, 0, stream>>>(pool_part, pooled);
    qkwin_kernel<<<512, 256, 0, stream>>>(pooled, qkv_w, qkv_b, qk_win);
    routing_kernel<<<512, 64, 0, stream>>>(qk_win, idxb);

    gemm_kernel<0><<<dim3(256, 6), 256, 0, stream>>>(
        ln1, wt_qkv, qkv_b, qkv, 32768, 768, 256, nullptr, nullptr, nullptr);

    lepe_kernel<<<dim3(512, 4), 256, 0, stream>>>(qkv, lepe_w, lepe_b, lepe);
    attn_kernel<<<dim3(512, 8), 512, 0, stream>>>(qkv, idxb, attn_out);

    resid1_ln2_kernel<<<32768, 256, 0, stream>>>(xp, attn_out, lepe, g1, n2g, n2b, xp1, zbuf);

    gemm_kernel<1><<<dim3(256, 8), 256, 0, stream>>>(
        zbuf, wt_m1, b1, hbuf, 32768, 1024, 256, nullptr, nullptr, nullptr);
    gemm_kernel<2><<<dim3(256, 2), 256, 0, stream>>>(
        hbuf, wt_m2, b2, nullptr, 32768, 256, 1024, xp1, g2, yout);

    out_xpose_kernel<<<512, 256, 0, stream>>>(yout, outp);
}

// Round 5
// 708.186 us; speedup vs baseline: 1.0008x; 1.0008x over previous
//
#include <hip/hip_runtime.h>

typedef unsigned short u16;
typedef __bf16 bf16x8 __attribute__((ext_vector_type(8)));
typedef short s16x4 __attribute__((ext_vector_type(4)));
typedef float f32x4 __attribute__((ext_vector_type(4)));

#define SCALE_ATT 0.0625f   // C^-0.5 = 1/16

static __device__ __forceinline__ u16 f2b(float f) {
    union { float f; unsigned u; } v; v.f = f;
    unsigned r = (v.u + 0x7fffu + ((v.u >> 16) & 1u)) >> 16;
    return (u16)r;
}
static __device__ __forceinline__ float b2f(u16 h) {
    union { unsigned u; float f; } v; v.u = ((unsigned)h) << 16;
    return v.f;
}

#if defined(__has_builtin)
#if __has_builtin(__builtin_amdgcn_mfma_f32_16x16x16bf16_1k)
#define HAVE_MFMA16 1
#endif
#endif

static __device__ __forceinline__ f32x4 mfma16(s16x4 a, s16x4 b, f32x4 c) {
#ifdef HAVE_MFMA16
    return __builtin_amdgcn_mfma_f32_16x16x16bf16_1k(a, b, c, 0, 0, 0);
#else
    f32x4 d;
    asm volatile("v_mfma_f32_16x16x16_bf16 %0, %1, %2, %3\n\ts_nop 7\n\ts_nop 7"
                 : "=v"(d) : "v"(a), "v"(b), "v"(c));
    return d;
#endif
}

// ---------------------------------------------------------------------------
// Weight transpose + bf16 cast: src [R][C] f32 -> dst [C][R] bf16
__global__ void wtrans_kernel(const float* __restrict__ src, u16* __restrict__ dst,
                              int R, int C) {
    int i = blockIdx.x * 256 + threadIdx.x;
    if (i >= R * C) return;
    int r = i / C, c = i % C;
    dst[(size_t)c * R + r] = f2b(src[i]);
}

// ---------------------------------------------------------------------------
// LN1 + NCHW->NHWC transpose. Block = (n,y). Writes xp (raw x, NHWC f32),
// ln1 (bf16 NHWC), and per-(y, window-col) pooled partial sums (fp32 LN vals).
__global__ __launch_bounds__(256) void ln_xpose_kernel(
    const float* __restrict__ x, const float* __restrict__ g, const float* __restrict__ b,
    float* __restrict__ xp, u16* __restrict__ ln1, float* __restrict__ pool_part) {
    __shared__ float xs[256][65];
    __shared__ float ps[4][64], ps2[4][64];
    __shared__ float mvmu[64], mvrs[64];
    int nb = blockIdx.x; int n = nb >> 6, y = nb & 63;
    int t = threadIdx.x;
    const float4* src = (const float4*)(x + ((size_t)(n * 256 + t) * 64 + y) * 64);
    for (int x4 = 0; x4 < 16; ++x4) {
        float4 v = src[x4];
        xs[t][x4 * 4 + 0] = v.x; xs[t][x4 * 4 + 1] = v.y;
        xs[t][x4 * 4 + 2] = v.z; xs[t][x4 * 4 + 3] = v.w;
    }
    __syncthreads();
    int part = t >> 6, l = t & 63;
    float s1 = 0.f, s2 = 0.f;
    for (int c = 0; c < 64; ++c) { float v = xs[part * 64 + c][l]; s1 += v; s2 += v * v; }
    ps[part][l] = s1; ps2[part][l] = s2;
    __syncthreads();
    if (t < 64) {
        float su = ps[0][t] + ps[1][t] + ps[2][t] + ps[3][t];
        float sq = ps2[0][t] + ps2[1][t] + ps2[2][t] + ps2[3][t];
        float mu = su * (1.f / 256.f);
        float var = sq * (1.f / 256.f) - mu * mu;
        mvmu[t] = mu; mvrs[t] = rsqrtf(var + 1e-6f);
    }
    __syncthreads();
    float gc = g[t], bc = b[t];
    size_t tokbase = (size_t)nb * 64;
    float pw = 0.f;
    for (int xx = 0; xx < 64; ++xx) {
        float raw = xs[t][xx];
        float val = (raw - mvmu[xx]) * mvrs[xx] * gc + bc;
        size_t tok = tokbase + xx;
        xp[tok * 256 + t] = raw;
        ln1[tok * 256 + t] = f2b(val);
        pw += val;
        if ((xx & 7) == 7) {
            pool_part[((size_t)nb * 8 + (xx >> 3)) * 256 + t] = pw;
            pw = 0.f;
        }
    }
}

// pooled[n][p][c] = mean over 64 window pixels (from y-row partials)
__global__ void pool_reduce_kernel(const float* __restrict__ pool_part,
                                   float* __restrict__ pooled) {
    int nb = blockIdx.x; int n = nb >> 6, p = nb & 63;
    int wi = p >> 3, wj = p & 7;
    int t = threadIdx.x;
    float s = 0.f;
    for (int r = 0; r < 8; ++r)
        s += pool_part[((size_t)((n * 64 + wi * 8 + r) * 8 + wj)) * 256 + t];
    pooled[(size_t)nb * 256 + t] = s * (1.f / 64.f);
}

// q_win/k_win = pooled @ Wq/Wk + b  (fp32, tiny). qk_win[nb][0:256]=q, [256:512]=k
__global__ void qkwin_kernel(const float* __restrict__ pooled,
                             const float* __restrict__ qkv_w, const float* __restrict__ qkv_b,
                             float* __restrict__ qk_win) {
    __shared__ float pr[256];
    int nb = blockIdx.x; int t = threadIdx.x;
    pr[t] = pooled[(size_t)nb * 256 + t];
    __syncthreads();
    float aq = qkv_b[t], ak = qkv_b[256 + t];
    for (int k = 0; k < 256; ++k) {
        float pv = pr[k];
        aq += pv * qkv_w[(size_t)k * 768 + t];
        ak += pv * qkv_w[(size_t)k * 768 + 256 + t];
    }
    qk_win[(size_t)nb * 512 + t] = aq;
    qk_win[(size_t)nb * 512 + 256 + t] = ak;
}

// top-4 window routing (sequential argmax == jax.lax.top_k tie rule: lowest idx)
__global__ void routing_kernel(const float* __restrict__ qk_win, int* __restrict__ idxp) {
    __shared__ float lg_[64];
    int nb = blockIdx.x; int n = nb >> 6;
    int t = threadIdx.x;  // 64 threads
    const float* qw = qk_win + (size_t)nb * 512;
    const float* kw = qk_win + (size_t)(n * 64 + t) * 512 + 256;
    float s = 0.f;
    for (int c = 0; c < 256; ++c) s += qw[c] * kw[c];
    lg_[t] = s * SCALE_ATT;
    __syncthreads();
    if (t == 0) {
        for (int j = 0; j < 4; ++j) {
            float best = -INFINITY; int bi = 0;
            for (int q = 0; q < 64; ++q) if (lg_[q] > best) { best = lg_[q]; bi = q; }
            idxp[nb * 4 + j] = bi;
            lg_[bi] = -INFINITY;
        }
    }
}

// ---------------------------------------------------------------------------
// bf16 GEMM: 128x128 tile, BK=32, 4 waves, 4x4 16x16 frags/wave (m93 ladder
// step). REG-STAGED global->LDS (proven R3 path; global_load_lds reverted
// after R4's 3.5x/26x fetch/write HBM amplification). Padded [rows][40] LDS.
// EPI 0: ->bf16. EPI 1: gelu(exact)->bf16. EPI 2: resid_out = resid_in + gamma*val
template <int EPI>
__global__ __launch_bounds__(256) void gemm_kernel(
    const u16* __restrict__ A, const u16* __restrict__ Bt,
    const float* __restrict__ bias, u16* __restrict__ outb,
    int M, int Nn, int K,
    const float* __restrict__ resid_in, const float* __restrict__ gamma,
    float* __restrict__ resid_out) {
    __shared__ u16 As[128][40];
    __shared__ u16 Bs[128][40];
    int t = threadIdx.x;
    int rowBase = blockIdx.x * 128, colBase = blockIdx.y * 128;
    int wid = t >> 6, lane = t & 63;
    int wr = (wid >> 1) * 64, wc = (wid & 1) * 64;
    int lr = lane & 15, g = lane >> 4;
    f32x4 acc[4][4] = {};
    int srow = t >> 2, sseg = t & 3;
    const u16* gA0 = A + (size_t)(rowBase + srow) * K + sseg * 8;
    const u16* gA1 = A + (size_t)(rowBase + srow + 64) * K + sseg * 8;
    const u16* gB0 = Bt + (size_t)(colBase + srow) * K + sseg * 8;
    const u16* gB1 = Bt + (size_t)(colBase + srow + 64) * K + sseg * 8;
    for (int k0 = 0; k0 < K; k0 += 32) {
        float4 a0 = *(const float4*)(gA0 + k0);
        float4 a1 = *(const float4*)(gA1 + k0);
        float4 b0 = *(const float4*)(gB0 + k0);
        float4 b1 = *(const float4*)(gB1 + k0);
        __syncthreads();                    // prev iter's reads done
        *(float4*)&As[srow][sseg * 8] = a0;
        *(float4*)&As[srow + 64][sseg * 8] = a1;
        *(float4*)&Bs[srow][sseg * 8] = b0;
        *(float4*)&Bs[srow + 64][sseg * 8] = b1;
        __syncthreads();                    // tile ready
        bf16x8 af[4], bfr[4];
        #pragma unroll
        for (int m = 0; m < 4; ++m)
            af[m] = *(const bf16x8*)&As[wr + m * 16 + lr][g * 8];
        #pragma unroll
        for (int nn = 0; nn < 4; ++nn)
            bfr[nn] = *(const bf16x8*)&Bs[wc + nn * 16 + lr][g * 8];
        #pragma unroll
        for (int m = 0; m < 4; ++m)
            #pragma unroll
            for (int nn = 0; nn < 4; ++nn)
                acc[m][nn] = __builtin_amdgcn_mfma_f32_16x16x32_bf16(af[m], bfr[nn], acc[m][nn], 0, 0, 0);
    }
    for (int m = 0; m < 4; ++m)
        for (int nn = 0; nn < 4; ++nn) {
            int col = colBase + wc + nn * 16 + lr;
            float bcol = bias[col];
            for (int r = 0; r < 4; ++r) {
                int row = rowBase + wr + m * 16 + g * 4 + r;
                float v = acc[m][nn][r] + bcol;
                if constexpr (EPI == 0) {
                    outb[(size_t)row * Nn + col] = f2b(v);
                } else if constexpr (EPI == 1) {
                    float gl = 0.5f * v * (1.f + erff(v * 0.70710678118654752f));
                    outb[(size_t)row * Nn + col] = f2b(gl);
                } else {
                    float yv = resid_in[(size_t)row * 256 + col] + gamma[col] * v;
                    resid_out[(size_t)row * 256 + col] = yv;
                }
            }
        }
}

// ---------------------------------------------------------------------------
// 5x5 depthwise conv on v (= qkv[..., 512:]) + bias -> lepe (bf16 NHWC)
// Register sliding-window: grid (512 rows, 4 ch-groups), thread = (16-x strip, ch).
__global__ __launch_bounds__(256) void lepe_kernel(
    const u16* __restrict__ qkv, const float* __restrict__ w,
    const float* __restrict__ bias, u16* __restrict__ lepe) {
    int nb = blockIdx.x, cg = blockIdx.y;
    int n = nb >> 6, y = nb & 63;
    int t = threadIdx.x;
    int c = cg * 64 + (t & 63);
    int x0 = (t >> 6) * 16;
    float wv[25];
    #pragma unroll
    for (int i = 0; i < 25; ++i) wv[i] = w[i * 256 + c];
    float bc = bias[c];
    const u16* vbase = qkv + 512 + c;
    size_t rowstr = (size_t)64 * 768;
    const u16* rbase = vbase + (size_t)(n * 64) * rowstr;
    bool rv[5];
    #pragma unroll
    for (int r = 0; r < 5; ++r) { int yy = y - 2 + r; rv[r] = (yy >= 0 && yy <= 63); }
    float win[5][5];
    #pragma unroll
    for (int r = 0; r < 5; ++r) {
        int yy = y - 2 + r;
        #pragma unroll
        for (int j = 0; j < 4; ++j) {
            int x2 = x0 - 2 + j;
            win[r][j] = (rv[r] && x2 >= 0) ? b2f(rbase[((size_t)yy * 64 + x2) * 768]) : 0.f;
        }
    }
    #pragma unroll
    for (int xi = 0; xi < 16; ++xi) {
        int xx = x0 + xi;
        int xl = xx + 2;
        #pragma unroll
        for (int r = 0; r < 5; ++r) {
            int yy = y - 2 + r;
            win[r][4] = (rv[r] && xl <= 63) ? b2f(rbase[((size_t)yy * 64 + xl) * 768]) : 0.f;
        }
        float s = bc;
        #pragma unroll
        for (int r = 0; r < 5; ++r)
            #pragma unroll
            for (int j = 0; j < 5; ++j)
                s = fmaf(wv[r * 5 + j], win[r][j], s);
        lepe[((size_t)nb * 64 + xx) * 256 + c] = f2b(s);
        #pragma unroll
        for (int r = 0; r < 5; ++r)
            #pragma unroll
            for (int j = 0; j < 4; ++j)
                win[r][j] = win[r][j + 1];
    }
}

// ---------------------------------------------------------------------------
// Routed window attention, swapped-QK^T in-register-softmax form.
// Grid (512 windows, 8 head-pairs), 512 threads = 8 waves.
__global__ __launch_bounds__(512) void attn_kernel(
    const u16* __restrict__ qkv, const int* __restrict__ idxp,
    float* __restrict__ attn_out) {
    __shared__ u16 qs[64][40];     // [pix][32ch], pad->40
    __shared__ u16 ks[256][40];    // [key][32ch], pad->40
    __shared__ u16 vts[32][256];   // [ch][key], XOR-swizzled cols
    __shared__ float os[64][36];   // [pix][32ch] f32 out-stage
    int nb = blockIdx.x, hg = blockIdx.y;
    int n = nb >> 6, p = nb & 63;
    int y0 = (p >> 3) * 8, x0 = (p & 7) * 8;
    int t = threadIdx.x;
    int w0 = idxp[nb * 4 + 0], w1 = idxp[nb * 4 + 1];
    int w2 = idxp[nb * 4 + 2], w3 = idxp[nb * 4 + 3];
    {   // stage Q: 64 tok x 32 ch, 8B per thread
        int tok = t >> 3, seg = t & 7;
        int tokg = (n * 64 + y0 + (tok >> 3)) * 64 + x0 + (tok & 7);
        *(uint2*)&qs[tok][seg * 4] =
            *(const uint2*)(qkv + (size_t)tokg * 768 + hg * 32 + seg * 4);
    }
    {   // stage K (rows) and V (transposed+swizzled): 32B per thread each
        int key = t & 255, half = t >> 8;
        int ws = (key >> 6) == 0 ? w0 : (key >> 6) == 1 ? w1 : (key >> 6) == 2 ? w2 : w3;
        int kp = key & 63;
        int tokk = (n * 64 + (ws >> 3) * 8 + (kp >> 3)) * 64 + (ws & 7) * 8 + (kp & 7);
        const u16* kbase = qkv + (size_t)tokk * 768 + 256 + hg * 32 + half * 16;
        *(float4*)&ks[key][half * 16] = *(const float4*)kbase;
        *(float4*)&ks[key][half * 16 + 8] = *(const float4*)(kbase + 8);
        const u16* vbase = kbase + 256;
        union { float4 f[2]; u16 u[16]; } vu;
        vu.f[0] = *(const float4*)vbase;
        vu.f[1] = *(const float4*)(vbase + 8);
        #pragma unroll
        for (int c2 = 0; c2 < 16; ++c2)
            vts[half * 16 + c2][key ^ (c2 << 2)] = vu.u[c2];
    }
    __syncthreads();

    int wid = t >> 6, lane = t & 63, lr = lane & 15, g = lane >> 4;
    int hh = wid & 1, q0 = (wid >> 1) * 16, c0 = hh * 16;
    f32x4 zf4 = {0.f, 0.f, 0.f, 0.f};
    s16x4 qf = *(const s16x4*)&qs[q0 + lr][c0 + g * 4];
    f32x4 sacc[16];
    #pragma unroll
    for (int kt = 0; kt < 16; ++kt) {
        s16x4 kf = *(const s16x4*)&ks[kt * 16 + lr][c0 + g * 4];
        sacc[kt] = mfma16(kf, qf, zf4);
    }
    // row max over 256 keys: 64 in-lane + xor16 + xor32
    float mx = -INFINITY;
    #pragma unroll
    for (int kt = 0; kt < 16; ++kt) {
        #pragma unroll
        for (int r = 0; r < 4; ++r) mx = fmaxf(mx, sacc[kt][r]);
    }
    mx = fmaxf(mx, __shfl_xor(mx, 16, 64));
    mx = fmaxf(mx, __shfl_xor(mx, 32, 64));
    const float k1 = 0.09016844005556021f;  // SCALE_ATT * log2(e)
    float dsum = 0.f;
    s16x4 pf[16];
    #pragma unroll
    for (int kt = 0; kt < 16; ++kt) {
        #pragma unroll
        for (int r = 0; r < 4; ++r) {
            float pv = exp2f((sacc[kt][r] - mx) * k1);
            dsum += pv;
            pf[kt][r] = (short)f2b(pv);
        }
    }
    dsum += __shfl_xor(dsum, 16, 64);
    dsum += __shfl_xor(dsum, 32, 64);
    float rden = 1.f / dsum;
    // PV: O^T[d][q] += V^T-frag x P-frag, two parallel accumulators
    f32x4 o0 = zf4, o1 = zf4;
    #pragma unroll
    for (int kt = 0; kt < 16; kt += 2) {
        s16x4 v0 = *(const s16x4*)&vts[c0 + lr][(kt * 16 + g * 4) ^ (lr << 2)];
        o0 = mfma16(v0, pf[kt], o0);
        s16x4 v1 = *(const s16x4*)&vts[c0 + lr][((kt + 1) * 16 + g * 4) ^ (lr << 2)];
        o1 = mfma16(v1, pf[kt + 1], o1);
    }
    #pragma unroll
    for (int r = 0; r < 4; ++r)
        os[q0 + lr][c0 + g * 4 + r] = (o0[r] + o1[r]) * rden;
    __syncthreads();
    {   // coalesced writeout: 64 tok x 32 ch f32
        int tok = t >> 3, cs = (t & 7) * 4;
        int tokg = (n * 64 + y0 + (tok >> 3)) * 64 + x0 + (tok & 7);
        *(float4*)(attn_out + (size_t)tokg * 256 + hg * 32 + cs) =
            *(const float4*)&os[tok][cs];
    }
}

// ---------------------------------------------------------------------------
// xp1 = xp + g1*(attn + lepe); LN2 -> z (bf16). Block = one token.
__global__ __launch_bounds__(256) void resid1_ln2_kernel(
    const float* __restrict__ xp, const float* __restrict__ attn,
    const u16* __restrict__ lepe, const float* __restrict__ g1,
    const float* __restrict__ n2g, const float* __restrict__ n2b,
    float* __restrict__ xp1, u16* __restrict__ z) {
    __shared__ float w1s[4], w2s[4];
    size_t tok = blockIdx.x;
    int t = threadIdx.x;
    float x1 = xp[tok * 256 + t] + g1[t] * (attn[tok * 256 + t] + b2f(lepe[tok * 256 + t]));
    xp1[tok * 256 + t] = x1;
    float s1 = x1, s2 = x1 * x1;
    for (int off = 1; off < 64; off <<= 1) {
        s1 += __shfl_xor(s1, off, 64);
        s2 += __shfl_xor(s2, off, 64);
    }
    int wid = t >> 6;
    if ((t & 63) == 0) { w1s[wid] = s1; w2s[wid] = s2; }
    __syncthreads();
    s1 = w1s[0] + w1s[1] + w1s[2] + w1s[3];
    s2 = w2s[0] + w2s[1] + w2s[2] + w2s[3];
    float mu = s1 * (1.f / 256.f);
    float var = s2 * (1.f / 256.f) - mu * mu;
    float rs = rsqrtf(var + 1e-6f);
    z[tok * 256 + t] = f2b((x1 - mu) * rs * n2g[t] + n2b[t]);
}

// NHWC f32 -> NCHW f32 output transpose
__global__ __launch_bounds__(256) void out_xpose_kernel(
    const float* __restrict__ yout, float* __restrict__ outp) {
    __shared__ float ys[256][65];
    int nb = blockIdx.x; int n = nb >> 6, y = nb & 63;
    int t = threadIdx.x;
    for (int xx = 0; xx < 64; ++xx)
        ys[t][xx] = yout[((size_t)nb * 64 + xx) * 256 + t];
    __syncthreads();
    float4* dst = (float4*)(outp + ((size_t)(n * 256 + t) * 64 + y) * 64);
    for (int x4 = 0; x4 < 16; ++x4) {
        float4 v = { ys[t][x4 * 4 + 0], ys[t][x4 * 4 + 1],
                     ys[t][x4 * 4 + 2], ys[t][x4 * 4 + 3] };
        dst[x4] = v;
    }
}

// ---------------------------------------------------------------------------
extern "C" void kernel_launch(void* const* d_in, const int* in_sizes, int n_in,
                              void* d_out, int out_size, void* d_ws, size_t ws_size,
                              hipStream_t stream) {
    (void)in_sizes; (void)n_in; (void)out_size; (void)ws_size;
    const float* x      = (const float*)d_in[0];
    const float* n1g    = (const float*)d_in[1];
    const float* n1b    = (const float*)d_in[2];
    const float* qkv_w  = (const float*)d_in[3];
    const float* qkv_b  = (const float*)d_in[4];
    const float* lepe_w = (const float*)d_in[5];
    const float* lepe_b = (const float*)d_in[6];
    const float* g1     = (const float*)d_in[7];
    const float* g2     = (const float*)d_in[8];
    const float* n2g    = (const float*)d_in[9];
    const float* n2b    = (const float*)d_in[10];
    const float* w1     = (const float*)d_in[11];
    const float* b1     = (const float*)d_in[12];
    const float* w2     = (const float*)d_in[13];
    const float* b2     = (const float*)d_in[14];
    float* outp = (float*)d_out;
    char* ws = (char*)d_ws;

    // workspace layout (total ~175 MB)
    float* xp        = (float*)(ws + 0);            // 33,554,432
    u16*   ln1       = (u16*)(ws + 33554432);       // 16,777,216
    u16*   qkv       = (u16*)(ws + 50331648);       // 50,331,648
    float* attn_out  = (float*)(ws + 100663296);    // 33,554,432 (reused as yout)
    u16*   lepe      = (u16*)(ws + 134217728);      // 16,777,216
    u16*   zbuf      = (u16*)(ws + 150994944);      // 16,777,216
    float* pool_part = (float*)(ws + 167772160);    //  4,194,304
    float* pooled    = (float*)(ws + 171966464);    //    524,288
    float* qk_win    = (float*)(ws + 172490752);    //  1,048,576
    int*   idxb      = (int*)(ws + 173539328);      //      8,192
    u16*   wt_qkv    = (u16*)(ws + 173547520);      //    393,216
    u16*   wt_m1     = (u16*)(ws + 173940736);      //    524,288
    u16*   wt_m2     = (u16*)(ws + 174465024);      //    524,288  (end 174,989,312)
    u16*   hbuf      = ln1;       // [32768][1024] bf16 reuses ln1+qkv region (exactly 64 MB)
    float* xp1       = outp;      // d_out used as scratch; fully overwritten by out_xpose
    float* yout      = attn_out;

    wtrans_kernel<<<768, 256, 0, stream>>>(qkv_w, wt_qkv, 256, 768);
    wtrans_kernel<<<1024, 256, 0, stream>>>(w1, wt_m1, 256, 1024);
    wtrans_kernel<<<1024, 256, 0, stream>>>(w2, wt_m2, 1024, 256);

    ln_xpose_kernel<<<512, 256, 0, stream>>>(x, n1g, n1b, xp, ln1, pool_part);
    pool_reduce_kernel<<<512, 256, 0, stream>>>(pool_part, pooled);
    qkwin_kernel<<<512, 256, 0, stream>>>(pooled, qkv_w, qkv_b, qk_win);
    routing_kernel<<<512, 64, 0, stream>>>(qk_win, idxb);

    gemm_kernel<0><<<dim3(256, 6), 256, 0, stream>>>(
        ln1, wt_qkv, qkv_b, qkv, 32768, 768, 256, nullptr, nullptr, nullptr);

    lepe_kernel<<<dim3(512, 4), 256, 0, stream>>>(qkv, lepe_w, lepe_b, lepe);
    attn_kernel<<<dim3(512, 8), 512, 0, stream>>>(qkv, idxb, attn_out);

    resid1_ln2_kernel<<<32768, 256, 0, stream>>>(xp, attn_out, lepe, g1, n2g, n2b, xp1, zbuf);

    gemm_kernel<1><<<dim3(256, 8), 256, 0, stream>>>(
        zbuf, wt_m1, b1, hbuf, 32768, 1024, 256, nullptr, nullptr, nullptr);
    gemm_kernel<2><<<dim3(256, 2), 256, 0, stream>>>(
        hbuf, wt_m2, b2, nullptr, 32768, 256, 1024, xp1, g2, yout);

    out_xpose_kernel<<<512, 256, 0, stream>>>(yout, outp);
}

// Round 6
// 331.458 us; speedup vs baseline: 2.1383x; 2.1366x over previous
//
#include <hip/hip_runtime.h>

typedef unsigned short u16;
typedef __bf16 bf16x8 __attribute__((ext_vector_type(8)));
typedef short s16x4 __attribute__((ext_vector_type(4)));
typedef float f32x4 __attribute__((ext_vector_type(4)));

#define SCALE_ATT 0.0625f   // C^-0.5 = 1/16

static __device__ __forceinline__ u16 f2b(float f) {
    union { float f; unsigned u; } v; v.f = f;
    unsigned r = (v.u + 0x7fffu + ((v.u >> 16) & 1u)) >> 16;
    return (u16)r;
}
static __device__ __forceinline__ float b2f(u16 h) {
    union { unsigned u; float f; } v; v.u = ((unsigned)h) << 16;
    return v.f;
}

#if defined(__has_builtin)
#if __has_builtin(__builtin_amdgcn_mfma_f32_16x16x16bf16_1k)
#define HAVE_MFMA16 1
#endif
#endif

static __device__ __forceinline__ f32x4 mfma16(s16x4 a, s16x4 b, f32x4 c) {
#ifdef HAVE_MFMA16
    return __builtin_amdgcn_mfma_f32_16x16x16bf16_1k(a, b, c, 0, 0, 0);
#else
    f32x4 d;
    asm volatile("v_mfma_f32_16x16x16_bf16 %0, %1, %2, %3\n\ts_nop 7\n\ts_nop 7"
                 : "=v"(d) : "v"(a), "v"(b), "v"(c));
    return d;
#endif
}

// ---------------------------------------------------------------------------
// Weight transpose + bf16 cast: src [R][C] f32 -> dst [C][R] bf16
__global__ void wtrans_kernel(const float* __restrict__ src, u16* __restrict__ dst,
                              int R, int C) {
    int i = blockIdx.x * 256 + threadIdx.x;
    if (i >= R * C) return;
    int r = i / C, c = i % C;
    dst[(size_t)c * R + r] = f2b(src[i]);
}

// ---------------------------------------------------------------------------
// LN1 + NCHW->NHWC transpose. Block = (n,y). Writes xp (raw x, NHWC f32),
// ln1 (bf16 NHWC), and per-(y, window-col) pooled partial sums (fp32 LN vals).
__global__ __launch_bounds__(256) void ln_xpose_kernel(
    const float* __restrict__ x, const float* __restrict__ g, const float* __restrict__ b,
    float* __restrict__ xp, u16* __restrict__ ln1, float* __restrict__ pool_part) {
    __shared__ float xs[256][65];
    __shared__ float ps[4][64], ps2[4][64];
    __shared__ float mvmu[64], mvrs[64];
    int nb = blockIdx.x; int n = nb >> 6, y = nb & 63;
    int t = threadIdx.x;
    const float4* src = (const float4*)(x + ((size_t)(n * 256 + t) * 64 + y) * 64);
    for (int x4 = 0; x4 < 16; ++x4) {
        float4 v = src[x4];
        xs[t][x4 * 4 + 0] = v.x; xs[t][x4 * 4 + 1] = v.y;
        xs[t][x4 * 4 + 2] = v.z; xs[t][x4 * 4 + 3] = v.w;
    }
    __syncthreads();
    int part = t >> 6, l = t & 63;
    float s1 = 0.f, s2 = 0.f;
    for (int c = 0; c < 64; ++c) { float v = xs[part * 64 + c][l]; s1 += v; s2 += v * v; }
    ps[part][l] = s1; ps2[part][l] = s2;
    __syncthreads();
    if (t < 64) {
        float su = ps[0][t] + ps[1][t] + ps[2][t] + ps[3][t];
        float sq = ps2[0][t] + ps2[1][t] + ps2[2][t] + ps2[3][t];
        float mu = su * (1.f / 256.f);
        float var = sq * (1.f / 256.f) - mu * mu;
        mvmu[t] = mu; mvrs[t] = rsqrtf(var + 1e-6f);
    }
    __syncthreads();
    float gc = g[t], bc = b[t];
    size_t tokbase = (size_t)nb * 64;
    float pw = 0.f;
    for (int xx = 0; xx < 64; ++xx) {
        float raw = xs[t][xx];
        float val = (raw - mvmu[xx]) * mvrs[xx] * gc + bc;
        size_t tok = tokbase + xx;
        xp[tok * 256 + t] = raw;
        ln1[tok * 256 + t] = f2b(val);
        pw += val;
        if ((xx & 7) == 7) {
            pool_part[((size_t)nb * 8 + (xx >> 3)) * 256 + t] = pw;
            pw = 0.f;
        }
    }
}

// pooled[n][p][c] = mean over 64 window pixels (from y-row partials)
__global__ void pool_reduce_kernel(const float* __restrict__ pool_part,
                                   float* __restrict__ pooled) {
    int nb = blockIdx.x; int n = nb >> 6, p = nb & 63;
    int wi = p >> 3, wj = p & 7;
    int t = threadIdx.x;
    float s = 0.f;
    for (int r = 0; r < 8; ++r)
        s += pool_part[((size_t)((n * 64 + wi * 8 + r) * 8 + wj)) * 256 + t];
    pooled[(size_t)nb * 256 + t] = s * (1.f / 64.f);
}

// q_win/k_win = pooled @ Wq/Wk + b  (fp32, tiny). qk_win[nb][0:256]=q, [256:512]=k
__global__ void qkwin_kernel(const float* __restrict__ pooled,
                             const float* __restrict__ qkv_w, const float* __restrict__ qkv_b,
                             float* __restrict__ qk_win) {
    __shared__ float pr[256];
    int nb = blockIdx.x; int t = threadIdx.x;
    pr[t] = pooled[(size_t)nb * 256 + t];
    __syncthreads();
    float aq = qkv_b[t], ak = qkv_b[256 + t];
    for (int k = 0; k < 256; ++k) {
        float pv = pr[k];
        aq += pv * qkv_w[(size_t)k * 768 + t];
        ak += pv * qkv_w[(size_t)k * 768 + 256 + t];
    }
    qk_win[(size_t)nb * 512 + t] = aq;
    qk_win[(size_t)nb * 512 + 256 + t] = ak;
}

// top-4 window routing (sequential argmax == jax.lax.top_k tie rule: lowest idx)
__global__ void routing_kernel(const float* __restrict__ qk_win, int* __restrict__ idxp) {
    __shared__ float lg_[64];
    int nb = blockIdx.x; int n = nb >> 6;
    int t = threadIdx.x;  // 64 threads
    const float* qw = qk_win + (size_t)nb * 512;
    const float* kw = qk_win + (size_t)(n * 64 + t) * 512 + 256;
    float s = 0.f;
    for (int c = 0; c < 256; ++c) s += qw[c] * kw[c];
    lg_[t] = s * SCALE_ATT;
    __syncthreads();
    if (t == 0) {
        for (int j = 0; j < 4; ++j) {
            float best = -INFINITY; int bi = 0;
            for (int q = 0; q < 64; ++q) if (lg_[q] > best) { best = lg_[q]; bi = q; }
            idxp[nb * 4 + j] = bi;
            lg_[bi] = -INFINITY;
        }
    }
}

// ---------------------------------------------------------------------------
// bf16 GEMM: 128x128 tile, BK=32, 4 waves, 4x4 16x16 frags/wave.
// Reg-staged global->LDS, padded [rows][40] LDS.
// NOTE: epilogue loops MUST be fully unrolled -- rolled loops runtime-index
// acc[][] which forces the accumulator into scratch (R4/R5: 2 GB HBM traffic,
// 410 us/dispatch, VGPR_Count 28). Rule #20.
// EPI 0: ->bf16. EPI 1: gelu(exact)->bf16. EPI 2: resid_out = resid_in + gamma*val
template <int EPI>
__global__ __launch_bounds__(256) void gemm_kernel(
    const u16* __restrict__ A, const u16* __restrict__ Bt,
    const float* __restrict__ bias, u16* __restrict__ outb,
    int M, int Nn, int K,
    const float* __restrict__ resid_in, const float* __restrict__ gamma,
    float* __restrict__ resid_out) {
    __shared__ u16 As[128][40];
    __shared__ u16 Bs[128][40];
    int t = threadIdx.x;
    int rowBase = blockIdx.x * 128, colBase = blockIdx.y * 128;
    int wid = t >> 6, lane = t & 63;
    int wr = (wid >> 1) * 64, wc = (wid & 1) * 64;
    int lr = lane & 15, g = lane >> 4;
    f32x4 acc[4][4] = {};
    int srow = t >> 2, sseg = t & 3;
    const u16* gA0 = A + (size_t)(rowBase + srow) * K + sseg * 8;
    const u16* gA1 = A + (size_t)(rowBase + srow + 64) * K + sseg * 8;
    const u16* gB0 = Bt + (size_t)(colBase + srow) * K + sseg * 8;
    const u16* gB1 = Bt + (size_t)(colBase + srow + 64) * K + sseg * 8;
    for (int k0 = 0; k0 < K; k0 += 32) {
        float4 a0 = *(const float4*)(gA0 + k0);
        float4 a1 = *(const float4*)(gA1 + k0);
        float4 b0 = *(const float4*)(gB0 + k0);
        float4 b1 = *(const float4*)(gB1 + k0);
        __syncthreads();                    // prev iter's reads done
        *(float4*)&As[srow][sseg * 8] = a0;
        *(float4*)&As[srow + 64][sseg * 8] = a1;
        *(float4*)&Bs[srow][sseg * 8] = b0;
        *(float4*)&Bs[srow + 64][sseg * 8] = b1;
        __syncthreads();                    // tile ready
        bf16x8 af[4], bfr[4];
        #pragma unroll
        for (int m = 0; m < 4; ++m)
            af[m] = *(const bf16x8*)&As[wr + m * 16 + lr][g * 8];
        #pragma unroll
        for (int nn = 0; nn < 4; ++nn)
            bfr[nn] = *(const bf16x8*)&Bs[wc + nn * 16 + lr][g * 8];
        #pragma unroll
        for (int m = 0; m < 4; ++m)
            #pragma unroll
            for (int nn = 0; nn < 4; ++nn)
                acc[m][nn] = __builtin_amdgcn_mfma_f32_16x16x32_bf16(af[m], bfr[nn], acc[m][nn], 0, 0, 0);
    }
    #pragma unroll
    for (int m = 0; m < 4; ++m)
        #pragma unroll
        for (int nn = 0; nn < 4; ++nn) {
            int col = colBase + wc + nn * 16 + lr;
            float bcol = bias[col];
            #pragma unroll
            for (int r = 0; r < 4; ++r) {
                int row = rowBase + wr + m * 16 + g * 4 + r;
                float v = acc[m][nn][r] + bcol;
                if constexpr (EPI == 0) {
                    outb[(size_t)row * Nn + col] = f2b(v);
                } else if constexpr (EPI == 1) {
                    float gl = 0.5f * v * (1.f + erff(v * 0.70710678118654752f));
                    outb[(size_t)row * Nn + col] = f2b(gl);
                } else {
                    float yv = resid_in[(size_t)row * 256 + col] + gamma[col] * v;
                    resid_out[(size_t)row * 256 + col] = yv;
                }
            }
        }
}

// ---------------------------------------------------------------------------
// 5x5 depthwise conv on v (= qkv[..., 512:]) + bias -> lepe (bf16 NHWC)
// Register sliding-window: grid (512 rows, 4 ch-groups), thread = (16-x strip, ch).
__global__ __launch_bounds__(256) void lepe_kernel(
    const u16* __restrict__ qkv, const float* __restrict__ w,
    const float* __restrict__ bias, u16* __restrict__ lepe) {
    int nb = blockIdx.x, cg = blockIdx.y;
    int n = nb >> 6, y = nb & 63;
    int t = threadIdx.x;
    int c = cg * 64 + (t & 63);
    int x0 = (t >> 6) * 16;
    float wv[25];
    #pragma unroll
    for (int i = 0; i < 25; ++i) wv[i] = w[i * 256 + c];
    float bc = bias[c];
    const u16* vbase = qkv + 512 + c;
    size_t rowstr = (size_t)64 * 768;
    const u16* rbase = vbase + (size_t)(n * 64) * rowstr;
    bool rv[5];
    #pragma unroll
    for (int r = 0; r < 5; ++r) { int yy = y - 2 + r; rv[r] = (yy >= 0 && yy <= 63); }
    float win[5][5];
    #pragma unroll
    for (int r = 0; r < 5; ++r) {
        int yy = y - 2 + r;
        #pragma unroll
        for (int j = 0; j < 4; ++j) {
            int x2 = x0 - 2 + j;
            win[r][j] = (rv[r] && x2 >= 0) ? b2f(rbase[((size_t)yy * 64 + x2) * 768]) : 0.f;
        }
    }
    #pragma unroll
    for (int xi = 0; xi < 16; ++xi) {
        int xx = x0 + xi;
        int xl = xx + 2;
        #pragma unroll
        for (int r = 0; r < 5; ++r) {
            int yy = y - 2 + r;
            win[r][4] = (rv[r] && xl <= 63) ? b2f(rbase[((size_t)yy * 64 + xl) * 768]) : 0.f;
        }
        float s = bc;
        #pragma unroll
        for (int r = 0; r < 5; ++r)
            #pragma unroll
            for (int j = 0; j < 5; ++j)
                s = fmaf(wv[r * 5 + j], win[r][j], s);
        lepe[((size_t)nb * 64 + xx) * 256 + c] = f2b(s);
        #pragma unroll
        for (int r = 0; r < 5; ++r)
            #pragma unroll
            for (int j = 0; j < 4; ++j)
                win[r][j] = win[r][j + 1];
    }
}

// ---------------------------------------------------------------------------
// Routed window attention, swapped-QK^T in-register-softmax form.
// Grid (512 windows, 8 head-pairs), 512 threads = 8 waves.
__global__ __launch_bounds__(512) void attn_kernel(
    const u16* __restrict__ qkv, const int* __restrict__ idxp,
    float* __restrict__ attn_out) {
    __shared__ u16 qs[64][40];     // [pix][32ch], pad->40
    __shared__ u16 ks[256][40];    // [key][32ch], pad->40
    __shared__ u16 vts[32][256];   // [ch][key], XOR-swizzled cols
    __shared__ float os[64][36];   // [pix][32ch] f32 out-stage
    int nb = blockIdx.x, hg = blockIdx.y;
    int n = nb >> 6, p = nb & 63;
    int y0 = (p >> 3) * 8, x0 = (p & 7) * 8;
    int t = threadIdx.x;
    int w0 = idxp[nb * 4 + 0], w1 = idxp[nb * 4 + 1];
    int w2 = idxp[nb * 4 + 2], w3 = idxp[nb * 4 + 3];
    {   // stage Q: 64 tok x 32 ch, 8B per thread
        int tok = t >> 3, seg = t & 7;
        int tokg = (n * 64 + y0 + (tok >> 3)) * 64 + x0 + (tok & 7);
        *(uint2*)&qs[tok][seg * 4] =
            *(const uint2*)(qkv + (size_t)tokg * 768 + hg * 32 + seg * 4);
    }
    {   // stage K (rows) and V (transposed+swizzled): 32B per thread each
        int key = t & 255, half = t >> 8;
        int ws = (key >> 6) == 0 ? w0 : (key >> 6) == 1 ? w1 : (key >> 6) == 2 ? w2 : w3;
        int kp = key & 63;
        int tokk = (n * 64 + (ws >> 3) * 8 + (kp >> 3)) * 64 + (ws & 7) * 8 + (kp & 7);
        const u16* kbase = qkv + (size_t)tokk * 768 + 256 + hg * 32 + half * 16;
        *(float4*)&ks[key][half * 16] = *(const float4*)kbase;
        *(float4*)&ks[key][half * 16 + 8] = *(const float4*)(kbase + 8);
        const u16* vbase = kbase + 256;
        union { float4 f[2]; u16 u[16]; } vu;
        vu.f[0] = *(const float4*)vbase;
        vu.f[1] = *(const float4*)(vbase + 8);
        #pragma unroll
        for (int c2 = 0; c2 < 16; ++c2)
            vts[half * 16 + c2][key ^ (c2 << 2)] = vu.u[c2];
    }
    __syncthreads();

    int wid = t >> 6, lane = t & 63, lr = lane & 15, g = lane >> 4;
    int hh = wid & 1, q0 = (wid >> 1) * 16, c0 = hh * 16;
    f32x4 zf4 = {0.f, 0.f, 0.f, 0.f};
    s16x4 qf = *(const s16x4*)&qs[q0 + lr][c0 + g * 4];
    f32x4 sacc[16];
    #pragma unroll
    for (int kt = 0; kt < 16; ++kt) {
        s16x4 kf = *(const s16x4*)&ks[kt * 16 + lr][c0 + g * 4];
        sacc[kt] = mfma16(kf, qf, zf4);
    }
    // row max over 256 keys: 64 in-lane + xor16 + xor32
    float mx = -INFINITY;
    #pragma unroll
    for (int kt = 0; kt < 16; ++kt) {
        #pragma unroll
        for (int r = 0; r < 4; ++r) mx = fmaxf(mx, sacc[kt][r]);
    }
    mx = fmaxf(mx, __shfl_xor(mx, 16, 64));
    mx = fmaxf(mx, __shfl_xor(mx, 32, 64));
    const float k1 = 0.09016844005556021f;  // SCALE_ATT * log2(e)
    float dsum = 0.f;
    s16x4 pf[16];
    #pragma unroll
    for (int kt = 0; kt < 16; ++kt) {
        #pragma unroll
        for (int r = 0; r < 4; ++r) {
            float pv = exp2f((sacc[kt][r] - mx) * k1);
            dsum += pv;
            pf[kt][r] = (short)f2b(pv);
        }
    }
    dsum += __shfl_xor(dsum, 16, 64);
    dsum += __shfl_xor(dsum, 32, 64);
    float rden = 1.f / dsum;
    // PV: O^T[d][q] += V^T-frag x P-frag, two parallel accumulators
    f32x4 o0 = zf4, o1 = zf4;
    #pragma unroll
    for (int kt = 0; kt < 16; kt += 2) {
        s16x4 v0 = *(const s16x4*)&vts[c0 + lr][(kt * 16 + g * 4) ^ (lr << 2)];
        o0 = mfma16(v0, pf[kt], o0);
        s16x4 v1 = *(const s16x4*)&vts[c0 + lr][((kt + 1) * 16 + g * 4) ^ (lr << 2)];
        o1 = mfma16(v1, pf[kt + 1], o1);
    }
    #pragma unroll
    for (int r = 0; r < 4; ++r)
        os[q0 + lr][c0 + g * 4 + r] = (o0[r] + o1[r]) * rden;
    __syncthreads();
    {   // coalesced writeout: 64 tok x 32 ch f32
        int tok = t >> 3, cs = (t & 7) * 4;
        int tokg = (n * 64 + y0 + (tok >> 3)) * 64 + x0 + (tok & 7);
        *(float4*)(attn_out + (size_t)tokg * 256 + hg * 32 + cs) =
            *(const float4*)&os[tok][cs];
    }
}

// ---------------------------------------------------------------------------
// xp1 = xp + g1*(attn + lepe); LN2 -> z (bf16). Block = one token.
__global__ __launch_bounds__(256) void resid1_ln2_kernel(
    const float* __restrict__ xp, const float* __restrict__ attn,
    const u16* __restrict__ lepe, const float* __restrict__ g1,
    const float* __restrict__ n2g, const float* __restrict__ n2b,
    float* __restrict__ xp1, u16* __restrict__ z) {
    __shared__ float w1s[4], w2s[4];
    size_t tok = blockIdx.x;
    int t = threadIdx.x;
    float x1 = xp[tok * 256 + t] + g1[t] * (attn[tok * 256 + t] + b2f(lepe[tok * 256 + t]));
    xp1[tok * 256 + t] = x1;
    float s1 = x1, s2 = x1 * x1;
    for (int off = 1; off < 64; off <<= 1) {
        s1 += __shfl_xor(s1, off, 64);
        s2 += __shfl_xor(s2, off, 64);
    }
    int wid = t >> 6;
    if ((t & 63) == 0) { w1s[wid] = s1; w2s[wid] = s2; }
    __syncthreads();
    s1 = w1s[0] + w1s[1] + w1s[2] + w1s[3];
    s2 = w2s[0] + w2s[1] + w2s[2] + w2s[3];
    float mu = s1 * (1.f / 256.f);
    float var = s2 * (1.f / 256.f) - mu * mu;
    float rs = rsqrtf(var + 1e-6f);
    z[tok * 256 + t] = f2b((x1 - mu) * rs * n2g[t] + n2b[t]);
}

// NHWC f32 -> NCHW f32 output transpose
__global__ __launch_bounds__(256) void out_xpose_kernel(
    const float* __restrict__ yout, float* __restrict__ outp) {
    __shared__ float ys[256][65];
    int nb = blockIdx.x; int n = nb >> 6, y = nb & 63;
    int t = threadIdx.x;
    for (int xx = 0; xx < 64; ++xx)
        ys[t][xx] = yout[((size_t)nb * 64 + xx) * 256 + t];
    __syncthreads();
    float4* dst = (float4*)(outp + ((size_t)(n * 256 + t) * 64 + y) * 64);
    for (int x4 = 0; x4 < 16; ++x4) {
        float4 v = { ys[t][x4 * 4 + 0], ys[t][x4 * 4 + 1],
                     ys[t][x4 * 4 + 2], ys[t][x4 * 4 + 3] };
        dst[x4] = v;
    }
}

// ---------------------------------------------------------------------------
extern "C" void kernel_launch(void* const* d_in, const int* in_sizes, int n_in,
                              void* d_out, int out_size, void* d_ws, size_t ws_size,
                              hipStream_t stream) {
    (void)in_sizes; (void)n_in; (void)out_size; (void)ws_size;
    const float* x      = (const float*)d_in[0];
    const float* n1g    = (const float*)d_in[1];
    const float* n1b    = (const float*)d_in[2];
    const float* qkv_w  = (const float*)d_in[3];
    const float* qkv_b  = (const float*)d_in[4];
    const float* lepe_w = (const float*)d_in[5];
    const float* lepe_b = (const float*)d_in[6];
    const float* g1     = (const float*)d_in[7];
    const float* g2     = (const float*)d_in[8];
    const float* n2g    = (const float*)d_in[9];
    const float* n2b    = (const float*)d_in[10];
    const float* w1     = (const float*)d_in[11];
    const float* b1     = (const float*)d_in[12];
    const float* w2     = (const float*)d_in[13];
    const float* b2     = (const float*)d_in[14];
    float* outp = (float*)d_out;
    char* ws = (char*)d_ws;

    // workspace layout (total ~175 MB)
    float* xp        = (float*)(ws + 0);            // 33,554,432
    u16*   ln1       = (u16*)(ws + 33554432);       // 16,777,216
    u16*   qkv       = (u16*)(ws + 50331648);       // 50,331,648
    float* attn_out  = (float*)(ws + 100663296);    // 33,554,432 (reused as yout)
    u16*   lepe      = (u16*)(ws + 134217728);      // 16,777,216
    u16*   zbuf      = (u16*)(ws + 150994944);      // 16,777,216
    float* pool_part = (float*)(ws + 167772160);    //  4,194,304
    float* pooled    = (float*)(ws + 171966464);    //    524,288
    float* qk_win    = (float*)(ws + 172490752);    //  1,048,576
    int*   idxb      = (int*)(ws + 173539328);      //      8,192
    u16*   wt_qkv    = (u16*)(ws + 173547520);      //    393,216
    u16*   wt_m1     = (u16*)(ws + 173940736);      //    524,288
    u16*   wt_m2     = (u16*)(ws + 174465024);      //    524,288  (end 174,989,312)
    u16*   hbuf      = ln1;       // [32768][1024] bf16 reuses ln1+qkv region (exactly 64 MB)
    float* xp1       = outp;      // d_out used as scratch; fully overwritten by out_xpose
    float* yout      = attn_out;

    wtrans_kernel<<<768, 256, 0, stream>>>(qkv_w, wt_qkv, 256, 768);
    wtrans_kernel<<<1024, 256, 0, stream>>>(w1, wt_m1, 256, 1024);
    wtrans_kernel<<<1024, 256, 0, stream>>>(w2, wt_m2, 1024, 256);

    ln_xpose_kernel<<<512, 256, 0, stream>>>(x, n1g, n1b, xp, ln1, pool_part);
    pool_reduce_kernel<<<512, 256, 0, stream>>>(pool_part, pooled);
    qkwin_kernel<<<512, 256, 0, stream>>>(pooled, qkv_w, qkv_b, qk_win);
    routing_kernel<<<512, 64, 0, stream>>>(qk_win, idxb);

    gemm_kernel<0><<<dim3(256, 6), 256, 0, stream>>>(
        ln1, wt_qkv, qkv_b, qkv, 32768, 768, 256, nullptr, nullptr, nullptr);

    lepe_kernel<<<dim3(512, 4), 256, 0, stream>>>(qkv, lepe_w, lepe_b, lepe);
    attn_kernel<<<dim3(512, 8), 512, 0, stream>>>(qkv, idxb, attn_out);

    resid1_ln2_kernel<<<32768, 256, 0, stream>>>(xp, attn_out, lepe, g1, n2g, n2b, xp1, zbuf);

    gemm_kernel<1><<<dim3(256, 8), 256, 0, stream>>>(
        zbuf, wt_m1, b1, hbuf, 32768, 1024, 256, nullptr, nullptr, nullptr);
    gemm_kernel<2><<<dim3(256, 2), 256, 0, stream>>>(
        hbuf, wt_m2, b2, nullptr, 32768, 256, 1024, xp1, g2, yout);

    out_xpose_kernel<<<512, 256, 0, stream>>>(yout, outp);
}